// Round 2
// baseline (75.158 us; speedup 1.0000x reference)
//
#include <hip/hip_runtime.h>
#include <math.h>

#define HH 4
#define DD 64
#define BS 32
#define SSEL 4

__device__ __forceinline__ float waveReduceSum(float v) {
    #pragma unroll
    for (int m = 1; m < 64; m <<= 1) v += __shfl_xor(v, m, 64);
    return v;
}

__device__ __forceinline__ float silu_f(float x) {
    // x * sigmoid(x)
    return x / (1.0f + __expf(-x));
}

// Kernel 1: per-(b, blk, h) wave computes block means of K and V.
// Tight layout: kc[((cbase_b + blk)*HH + h)*DD + d]
__global__ void nsa_compress(const float* __restrict__ kin, const float* __restrict__ vin,
                             const int* __restrict__ offs, int B, int nbcap,
                             float* __restrict__ kc, float* __restrict__ vc) {
    int wid  = (blockIdx.x * blockDim.x + threadIdx.x) >> 6;
    int lane = threadIdx.x & 63;
    if (wid >= B * nbcap * HH) return;
    int h   = wid % HH;
    int blk = (wid / HH) % nbcap;
    int b   = wid / (HH * nbcap);
    int off = offs[b];
    int n   = offs[b + 1] - off;
    int ncmp = (n + BS - 1) / BS;
    if (blk >= ncmp) return;
    int cbase = 0;
    for (int i = 0; i < b; ++i) cbase += (offs[i + 1] - offs[i] + BS - 1) / BS;

    const float* kp = kin + (size_t)(off + blk * BS) * (HH * DD) + h * DD + lane;
    const float* vp = vin + (size_t)(off + blk * BS) * (HH * DD) + h * DD + lane;
    float ks = 0.f, vs = 0.f;
    int rmax = min(BS, n - blk * BS);
    for (int r = 0; r < rmax; ++r) {
        ks += kp[(size_t)r * HH * DD];
        vs += vp[(size_t)r * HH * DD];
    }
    size_t ci = ((size_t)(cbase + blk) * HH + h) * DD + lane;
    kc[ci] = ks * (1.0f / BS);
    vc[ci] = vs * (1.0f / BS);
}

// Kernel 2: one wave per (t, h). lane = d.
__global__ void nsa_main(const float* __restrict__ q, const float* __restrict__ k,
                         const float* __restrict__ v, const float* __restrict__ gc,
                         const float* __restrict__ gs, const int* __restrict__ offs,
                         const float* __restrict__ kc, const float* __restrict__ vc,
                         int B, int T, float* __restrict__ out) {
    int wid  = (blockIdx.x * blockDim.x + threadIdx.x) >> 6;
    int lane = threadIdx.x & 63;
    if (wid >= T * HH) return;
    int h = wid % HH;
    int t = wid / HH;

    int b = 0;
    while (t >= offs[b + 1]) ++b;
    int off  = offs[b];
    int lq   = t - off;
    int qblk = lq >> 5;
    int cbase = 0;
    for (int i = 0; i < b; ++i) cbase += (offs[i + 1] - offs[i] + BS - 1) / BS;

    const float scale = 0.125f;  // D^-0.5
    float qv = q[(size_t)t * (HH * DD) + h * DD + lane] * scale;

    // ---- compressed-block attention + online top-4 selection ----
    float topv[SSEL];
    int   topi[SSEL];
    #pragma unroll
    for (int j = 0; j < SSEL; ++j) { topv[j] = -INFINITY; topi[j] = -1; }

    float acc = 0.f;
    for (int blk = 0; blk <= qblk; ++blk) {
        size_t ci = ((size_t)(cbase + blk) * HH + h) * DD + lane;
        float s = waveReduceSum(qv * kc[ci]);     // wave-uniform after butterfly
        acc += silu_f(s) * vc[ci];
        if (s > topv[SSEL - 1]) {                 // strict >: lower block index wins ties
            float cv = s; int ci2 = blk;
            #pragma unroll
            for (int j = 0; j < SSEL; ++j) {
                if (cv > topv[j]) {
                    float tv = topv[j]; int ti = topi[j];
                    topv[j] = cv; topi[j] = ci2;
                    cv = tv; ci2 = ti;
                }
            }
        }
    }
    size_t obase = (size_t)t * (HH * DD) + h * DD + lane;
    out[obase] = acc * gc[t * HH + h];

    // ---- selection attention over top-4 blocks, element-causal ----
    float accs = 0.f;
    #pragma unroll
    for (int si = 0; si < SSEL; ++si) {
        int blk = topi[si];
        if (blk < 0) continue;                    // fewer than 4 causal blocks
        int rmax = min(BS - 1, lq - blk * BS);    // tpos <= lq (implies tpos < n)
        const float* kp = k + (size_t)(off + blk * BS) * (HH * DD) + h * DD;
        const float* vp = v + (size_t)(off + blk * BS) * (HH * DD) + h * DD;
        for (int r = 0; r <= rmax; ++r) {
            float s = waveReduceSum(qv * kp[(size_t)r * HH * DD + lane]);
            accs += silu_f(s) * vp[(size_t)r * HH * DD + lane];
        }
    }
    out[(size_t)T * HH * DD + obase] = accs * gs[t * HH + h];
}

extern "C" void kernel_launch(void* const* d_in, const int* in_sizes, int n_in,
                              void* d_out, int out_size, void* d_ws, size_t ws_size,
                              hipStream_t stream) {
    const float* q    = (const float*)d_in[0];
    const float* k    = (const float*)d_in[1];
    const float* v    = (const float*)d_in[2];
    const float* gc   = (const float*)d_in[3];
    const float* gs   = (const float*)d_in[4];
    const int*   offs = (const int*)d_in[5];   // JAX default: int32 on device

    int B = in_sizes[5] - 1;
    int T = out_size / (2 * HH * DD);
    int nbcap = (T + BS - 1) / BS;          // upper bound on blocks of any batch

    // workspace: kc and vc, tight block layout (<= nbcap + B blocks total)
    // total = 2 * (nbcap+B) * HH * DD * 4 bytes  (~110 KB at T=1600)
    size_t cmp_elems = (size_t)(nbcap + B) * HH * DD;
    float* kc = (float*)d_ws;
    float* vc = kc + cmp_elems;

    dim3 blk(256);
    int waves1 = B * nbcap * HH;
    dim3 g1((unsigned)((waves1 * 64 + 255) / 256));
    nsa_compress<<<g1, blk, 0, stream>>>(k, v, offs, B, nbcap, kc, vc);

    int waves2 = T * HH;
    dim3 g2((unsigned)((waves2 * 64 + 255) / 256));
    nsa_main<<<g2, blk, 0, stream>>>(q, k, v, gc, gs, offs, kc, vc, B, T, (float*)d_out);
}

// Round 3
// 49.106 us; speedup vs baseline: 1.5305x; 1.5305x over previous
//
#include <hip/hip_runtime.h>
#include <math.h>

#define HH 4
#define DD 64
#define BS 32
#define SSEL 4
#define STRIDE (HH * DD)
#define IDX_INVALID 0x7FFFFFFF

__device__ __forceinline__ float silu_f(float x) {
    return x / (1.0f + __expf(-x));
}

// Kernel 1: per-(b, blk, h) wave computes block means of K and V. lane = d.
// Layout: kc[((cbase_b + blk)*HH + h)*DD + d]
__global__ void nsa_compress(const float* __restrict__ kin, const float* __restrict__ vin,
                             const int* __restrict__ offs, int B, int nbcap,
                             float* __restrict__ kc, float* __restrict__ vc) {
    int wid  = (blockIdx.x * blockDim.x + threadIdx.x) >> 6;
    int lane = threadIdx.x & 63;
    if (wid >= B * nbcap * HH) return;
    int h   = wid % HH;
    int blk = (wid / HH) % nbcap;
    int b   = wid / (HH * nbcap);
    int off = offs[b];
    int n   = offs[b + 1] - off;
    int ncmp = (n + BS - 1) / BS;
    if (blk >= ncmp) return;
    int cbase = 0;
    for (int i = 0; i < b; ++i) cbase += (offs[i + 1] - offs[i] + BS - 1) / BS;

    const float* kp = kin + (size_t)(off + blk * BS) * STRIDE + h * DD + lane;
    const float* vp = vin + (size_t)(off + blk * BS) * STRIDE + h * DD + lane;
    float ks = 0.f, vs = 0.f;
    int rmax = min(BS, n - blk * BS);
    #pragma unroll 8
    for (int r = 0; r < rmax; ++r) {
        ks += kp[(size_t)r * STRIDE];
        vs += vp[(size_t)r * STRIDE];
    }
    size_t ci = ((size_t)(cbase + blk) * HH + h) * DD + lane;
    kc[ci] = ks * (1.0f / BS);
    vc[ci] = vs * (1.0f / BS);
}

// Kernel 2: one wave per (t, h). Scoring: lane = key. PV: lane = d.
__global__ __launch_bounds__(256) void nsa_main(
        const float* __restrict__ q, const float* __restrict__ k,
        const float* __restrict__ v, const float* __restrict__ gc,
        const float* __restrict__ gs, const int* __restrict__ offs,
        const float* __restrict__ kc, const float* __restrict__ vc,
        int B, int T, float* __restrict__ out) {
    __shared__ float lds_q[4][DD];
    int lane = threadIdx.x & 63;
    int wvb  = threadIdx.x >> 6;
    int wid  = blockIdx.x * 4 + wvb;
    bool active = wid < T * HH;

    int h = 0, t = 0, b = 0, off = 0, lq = 0, qblk = 0, cbase = 0, n = 64;
    const float scale = 0.125f;  // D^-0.5
    if (active) {
        h = wid % HH;
        t = wid / HH;
        while (t >= offs[b + 1]) ++b;
        off  = offs[b];
        n    = offs[b + 1] - off;
        lq   = t - off;
        qblk = lq >> 5;
        for (int i = 0; i < b; ++i) cbase += (offs[i + 1] - offs[i] + BS - 1) / BS;
        // stage scaled q into LDS (lane = d)
        lds_q[wvb][lane] = q[(size_t)t * STRIDE + h * DD + lane] * scale;
    }
    __syncthreads();
    if (!active) return;

    const float*  sq  = lds_q[wvb];
    const float4* sq4 = (const float4*)sq;

    // ---------- compressed-block attention + top-4 ----------
    float topv[SSEL];
    int   topi[SSEL];
    #pragma unroll
    for (int j = 0; j < SSEL; ++j) { topv[j] = -INFINITY; topi[j] = IDX_INVALID; }

    int nb_c = qblk + 1;               // causal compressed blocks
    float o_cmp = 0.f;
    int blkq = lane >> 2;              // 0..15  (block within batch)
    int dq   = lane & 3;               // d-quarter

    for (int base = 0; base < nb_c; base += 16) {
        int  blk    = base + blkq;
        bool bvalid = blk < nb_c;
        int  cblk   = bvalid ? (cbase + blk) : cbase;
        const float4* kcp = (const float4*)(kc + (size_t)cblk * STRIDE + h * DD + dq * 16);
        float s = 0.f;
        #pragma unroll
        for (int j = 0; j < 4; ++j) {
            float4 kk = kcp[j];
            float4 qq = sq4[dq * 4 + j];
            s += kk.x * qq.x + kk.y * qq.y + kk.z * qq.z + kk.w * qq.w;
        }
        // reduce the 4 d-quarters (groups of 4 lanes; all 4 end up with full s)
        s += __shfl_xor(s, 1, 64);
        s += __shfl_xor(s, 2, 64);

        float sc = bvalid ? s : -INFINITY;
        float p  = bvalid ? silu_f(s) : 0.f;

        // top-4 within this batch: 4 masked max-butterflies over the 16 groups
        float ms_s = sc;
        int   ms_i = bvalid ? blk : IDX_INVALID;
        #pragma unroll
        for (int rnd = 0; rnd < SSEL; ++rnd) {
            float rs = ms_s; int ri = ms_i;
            #pragma unroll
            for (int m = 4; m < 64; m <<= 1) {
                float os = __shfl_xor(rs, m, 64);
                int   oi = __shfl_xor(ri, m, 64);
                if (os > rs || (os == rs && oi < ri)) { rs = os; ri = oi; }
            }
            // (rs, ri) uniform winner of this round
            if (ri != IDX_INVALID) {
                float cv = rs; int cix = ri;
                #pragma unroll
                for (int j = 0; j < SSEL; ++j) {
                    if (cv > topv[j] || (cv == topv[j] && cix < topi[j])) {
                        float tv = topv[j]; int ti = topi[j];
                        topv[j] = cv; topi[j] = cix;
                        cv = tv; cix = ti;
                    }
                }
            }
            if (ms_i == ri) { ms_s = -INFINITY; ms_i = IDX_INVALID; }  // mask winner
        }

        // PV for this batch (lane = d): broadcast p from lane j*4
        int cnt = min(16, nb_c - base);
        const float* vcb = vc + ((size_t)(cbase + base) * HH + h) * DD + lane;
        for (int j = 0; j < cnt; ++j) {
            float pj = __shfl(p, j * 4, 64);
            o_cmp += pj * vcb[(size_t)j * HH * DD];
        }
    }

    size_t obase = (size_t)t * STRIDE + h * DD + lane;
    out[obase] = o_cmp * gc[t * HH + h];

    // ---------- selection attention over top-4 blocks ----------
    int sel[SSEL]; int nsel = 0;
    #pragma unroll
    for (int j = 0; j < SSEL; ++j)
        if (topi[j] != IDX_INVALID) sel[nsel++] = topi[j];

    float o_slc = 0.f;
    int n1 = n - 1;
    const float* vb = v + (size_t)off * STRIDE + h * DD + lane;

    for (int pass = 0; pass < nsel; pass += 2) {
        int blkA = sel[pass];
        int blkB = (pass + 1 < nsel) ? sel[pass + 1] : -1;
        int half = lane >> 5;
        int r    = lane & 31;
        int myblk = half ? blkB : blkA;
        bool valid = (myblk >= 0) && (myblk * BS + r) <= lq;
        int  tpos  = valid ? (myblk * BS + r) : 0;

        // score: lane = key, stream own K row, q broadcast from LDS
        const float4* krow = (const float4*)(k + (size_t)(off + tpos) * STRIDE + h * DD);
        float s = 0.f;
        #pragma unroll
        for (int j = 0; j < DD / 4; ++j) {
            float4 kk = krow[j];
            float4 qq = sq4[j];
            s += kk.x * qq.x + kk.y * qq.y + kk.z * qq.z + kk.w * qq.w;
        }
        float p = valid ? silu_f(s) : 0.f;

        // PV: lane = d; p broadcast via literal-index shfl (readlane)
        #pragma unroll
        for (int j = 0; j < BS; ++j) {
            float pj = __shfl(p, j, 64);
            int   tp = min(blkA * BS + j, n1);
            o_slc += pj * vb[(size_t)tp * STRIDE];
        }
        if (blkB >= 0) {
            #pragma unroll
            for (int j = 0; j < BS; ++j) {
                float pj = __shfl(p, BS + j, 64);
                int   tp = min(blkB * BS + j, n1);
                o_slc += pj * vb[(size_t)tp * STRIDE];
            }
        }
    }
    out[(size_t)T * STRIDE + obase] = o_slc * gs[t * HH + h];
}

extern "C" void kernel_launch(void* const* d_in, const int* in_sizes, int n_in,
                              void* d_out, int out_size, void* d_ws, size_t ws_size,
                              hipStream_t stream) {
    const float* q    = (const float*)d_in[0];
    const float* k    = (const float*)d_in[1];
    const float* v    = (const float*)d_in[2];
    const float* gc   = (const float*)d_in[3];
    const float* gs   = (const float*)d_in[4];
    const int*   offs = (const int*)d_in[5];   // JAX default x64-off: int32

    int B = in_sizes[5] - 1;
    int T = out_size / (2 * STRIDE);
    int nbcap = (T + BS - 1) / BS;

    size_t cmp_elems = (size_t)(nbcap + B) * STRIDE;
    float* kc = (float*)d_ws;
    float* vc = kc + cmp_elems;

    dim3 blk(256);
    int waves1 = B * nbcap * HH;
    dim3 g1((unsigned)((waves1 * 64 + 255) / 256));
    nsa_compress<<<g1, blk, 0, stream>>>(k, v, offs, B, nbcap, kc, vc);

    int waves2 = T * HH;
    dim3 g2((unsigned)((waves2 + 3) / 4));
    nsa_main<<<g2, blk, 0, stream>>>(q, k, v, gc, gs, offs, kc, vc, B, T, (float*)d_out);
}

// Round 4
// 42.710 us; speedup vs baseline: 1.7597x; 1.1498x over previous
//
#include <hip/hip_runtime.h>
#include <math.h>

#define HH 4
#define DD 64
#define BS 32
#define SSEL 4
#define STRIDE (HH * DD)
#define MAXNB 64   // supports seqlen <= 2048; harness max is 512 (16 blocks)

__device__ __forceinline__ float silu_f(float x) {
    return x / (1.0f + __expf(-x));
}

// Kernel 1: per-(b, blk, h, k-or-v) wave computes one block mean.
// lane = (rowgroup 0..3, d16 0..15), float4 per lane; 8 rows per rowgroup.
__global__ __launch_bounds__(256) void nsa_compress(
        const float* __restrict__ kin, const float* __restrict__ vin,
        const int* __restrict__ offs, int B, int nbcap,
        float* __restrict__ kc, float* __restrict__ vc) {
    int wid  = (blockIdx.x * blockDim.x + threadIdx.x) >> 6;
    int lane = threadIdx.x & 63;
    if (wid >= B * nbcap * HH * 2) return;
    int kind = wid & 1;
    int rest = wid >> 1;
    int h    = rest % HH;
    int blk  = (rest / HH) % nbcap;
    int b    = rest / (HH * nbcap);
    int off  = offs[b];
    int n    = offs[b + 1] - off;
    int ncmp = (n + BS - 1) / BS;
    if (blk >= ncmp) return;
    int cbase = 0;
    for (int i = 0; i < b; ++i) cbase += (offs[i + 1] - offs[i] + BS - 1) / BS;

    int rg = lane >> 4, d16 = lane & 15;
    const float* src = kind ? vin : kin;
    const float4* sp = (const float4*)(src + (size_t)(off + blk * BS) * STRIDE + h * DD + d16 * 4);
    int rmax = min(BS, n - blk * BS);
    float4 acc = {0.f, 0.f, 0.f, 0.f};
    #pragma unroll
    for (int i = 0; i < 8; ++i) {
        int row = rg * 8 + i;
        if (row < rmax) {
            float4 x = sp[(size_t)row * (STRIDE / 4)];
            acc.x += x.x; acc.y += x.y; acc.z += x.z; acc.w += x.w;
        }
    }
    #pragma unroll
    for (int m = 16; m <= 32; m <<= 1) {
        acc.x += __shfl_xor(acc.x, m, 64);
        acc.y += __shfl_xor(acc.y, m, 64);
        acc.z += __shfl_xor(acc.z, m, 64);
        acc.w += __shfl_xor(acc.w, m, 64);
    }
    if (rg == 0) {
        float4 r;
        r.x = acc.x * (1.f / BS); r.y = acc.y * (1.f / BS);
        r.z = acc.z * (1.f / BS); r.w = acc.w * (1.f / BS);
        float* dst = (kind ? vc : kc) + ((size_t)(cbase + blk) * HH + h) * DD + d16 * 4;
        *(float4*)dst = r;
    }
}

// Kernel 2: one 4-wave workgroup per (t, h).
__global__ __launch_bounds__(256) void nsa_fused(
        const float* __restrict__ q, const float* __restrict__ k,
        const float* __restrict__ v, const float* __restrict__ gc,
        const float* __restrict__ gs, const int* __restrict__ offs,
        const float* __restrict__ kc, const float* __restrict__ vc,
        int B, int T, int G, int smap, float* __restrict__ out) {
    __shared__ float sq[DD];
    __shared__ float scores[MAXNB];
    __shared__ float part[8][DD];   // [0..3]=cmp partial per wave, [4..7]=slc

    int g = (int)(((long long)blockIdx.x * smap) % G);   // load-balance remap
    int h = g % HH, t = g / HH;
    int lane = threadIdx.x & 63, w = threadIdx.x >> 6;

    int b = 0;
    while (t >= offs[b + 1]) ++b;
    int off = offs[b], n = offs[b + 1] - off;
    int lq = t - off, qblk = lq >> 5;
    int cbase = 0;
    for (int i = 0; i < b; ++i) cbase += (offs[i + 1] - offs[i] + BS - 1) / BS;
    int nb_c = qblk + 1;
    const float scale = 0.125f;  // D^-0.5

    if (w == 0) sq[lane] = q[(size_t)t * STRIDE + h * DD + lane] * scale;
    __syncthreads();
    const float4* sq4 = (const float4*)sq;

    // ---------- phase 1: compressed-block scores -> LDS ----------
    int bl = lane >> 4, d16 = lane & 15;
    for (int blk0 = 0; blk0 < nb_c; blk0 += 16) {
        int blk = blk0 + w * 4 + bl;
        if (blk < nb_c) {   // whole 16-lane group uniform -> shuffles safe
            const float4* kcp = (const float4*)(kc + ((size_t)(cbase + blk) * HH + h) * DD + d16 * 4);
            float4 kk = *kcp;
            float4 qq = sq4[d16];
            float s = kk.x * qq.x + kk.y * qq.y + kk.z * qq.z + kk.w * qq.w;
            s += __shfl_xor(s, 1, 64);
            s += __shfl_xor(s, 2, 64);
            s += __shfl_xor(s, 4, 64);
            s += __shfl_xor(s, 8, 64);
            if (d16 == 0 && blk < MAXNB) scores[blk] = s;
        }
    }
    __syncthreads();

    // ---------- phase 2a: top-4 via per-lane rank + ballot ----------
    float sl = scores[lane < nb_c ? lane : 0];
    int rank = 0;
    for (int j = 0; j < nb_c; ++j) {
        float sj = scores[j];
        rank += (sj > sl) || (sj == sl && j < lane);
    }
    unsigned long long mask = __ballot(lane < nb_c && rank < SSEL);
    unsigned long long m = mask;
    for (int j = 0; j < w; ++j) m &= (m - 1);
    int selw = m ? (__ffsll((long long)m) - 1) : -1;   // wave w's selected block

    // ---------- phase 2b: cmp PV (each lane: one block x float4 of d) ----------
    float4 acc = {0.f, 0.f, 0.f, 0.f};
    for (int blk0 = 0; blk0 < nb_c; blk0 += 16) {
        int blk = blk0 + w * 4 + bl;
        if (blk < nb_c) {
            float p = silu_f(scores[blk]);
            float4 vv = *(const float4*)(vc + ((size_t)(cbase + blk) * HH + h) * DD + d16 * 4);
            acc.x += p * vv.x; acc.y += p * vv.y; acc.z += p * vv.z; acc.w += p * vv.w;
        }
    }
    #pragma unroll
    for (int mm = 16; mm <= 32; mm <<= 1) {
        acc.x += __shfl_xor(acc.x, mm, 64);
        acc.y += __shfl_xor(acc.y, mm, 64);
        acc.z += __shfl_xor(acc.z, mm, 64);
        acc.w += __shfl_xor(acc.w, mm, 64);
    }
    if (lane < 16) *(float4*)&part[w][lane * 4] = acc;

    // ---------- phase 3: slc attention, one selected block per wave ----------
    float4 sacc = {0.f, 0.f, 0.f, 0.f};
    if (selw >= 0) {
        int r = lane & 31, half = lane >> 5;
        int tpos = selw * BS + r;                       // < n (n % 32 == 0, selw <= qblk)
        const float4* krow = (const float4*)(k + (size_t)(off + min(tpos, n - 1)) * STRIDE + h * DD + half * 32);
        float s = 0.f;
        #pragma unroll
        for (int j = 0; j < 8; ++j) {
            float4 kk = krow[j];
            float4 qq = sq4[half * 8 + j];
            s += kk.x * qq.x + kk.y * qq.y + kk.z * qq.z + kk.w * qq.w;
        }
        s += __shfl_xor(s, 32, 64);
        float p = (tpos <= lq) ? silu_f(s) : 0.f;

        int kg = lane >> 4;                             // keys kg*8 .. kg*8+7
        #pragma unroll
        for (int i = 0; i < 8; ++i) {
            int key = kg * 8 + i;
            float pj = __shfl(p, key, 64);
            int row = min(selw * BS + key, n - 1);
            float4 vv = *(const float4*)(v + (size_t)(off + row) * STRIDE + h * DD + d16 * 4);
            sacc.x += pj * vv.x; sacc.y += pj * vv.y; sacc.z += pj * vv.z; sacc.w += pj * vv.w;
        }
        #pragma unroll
        for (int mm = 16; mm <= 32; mm <<= 1) {
            sacc.x += __shfl_xor(sacc.x, mm, 64);
            sacc.y += __shfl_xor(sacc.y, mm, 64);
            sacc.z += __shfl_xor(sacc.z, mm, 64);
            sacc.w += __shfl_xor(sacc.w, mm, 64);
        }
    }
    if (lane < 16) *(float4*)&part[4 + w][lane * 4] = sacc;
    __syncthreads();

    // ---------- final: reduce 4 wave-partials, gate, write ----------
    if (w == 0) {
        float o = part[0][lane] + part[1][lane] + part[2][lane] + part[3][lane];
        out[(size_t)t * STRIDE + h * DD + lane] = o * gc[t * HH + h];
    } else if (w == 1) {
        float o = part[4][lane] + part[5][lane] + part[6][lane] + part[7][lane];
        out[(size_t)T * STRIDE + (size_t)t * STRIDE + h * DD + lane] = o * gs[t * HH + h];
    }
}

extern "C" void kernel_launch(void* const* d_in, const int* in_sizes, int n_in,
                              void* d_out, int out_size, void* d_ws, size_t ws_size,
                              hipStream_t stream) {
    const float* q    = (const float*)d_in[0];
    const float* k    = (const float*)d_in[1];
    const float* v    = (const float*)d_in[2];
    const float* gc   = (const float*)d_in[3];
    const float* gs   = (const float*)d_in[4];
    const int*   offs = (const int*)d_in[5];   // JAX x64-off: int32 on device

    int B = in_sizes[5] - 1;
    int T = out_size / (2 * STRIDE);
    int nbcap = (T + BS - 1) / BS;

    size_t cmp_elems = (size_t)(nbcap + B) * STRIDE;
    float* kc = (float*)d_ws;
    float* vc = kc + cmp_elems;

    dim3 blk(256);
    int waves1 = B * nbcap * HH * 2;
    dim3 g1((unsigned)((waves1 * 64 + 255) / 256));
    nsa_compress<<<g1, blk, 0, stream>>>(k, v, offs, B, nbcap, kc, vc);

    int G = T * HH;
    int smap = 61;
    if (G % smap == 0) smap = 67;
    if (G % smap == 0) smap = 71;
    nsa_fused<<<dim3((unsigned)G), blk, 0, stream>>>(q, k, v, gc, gs, offs, kc, vc,
                                                     B, T, G, smap, (float*)d_out);
}